// Round 14
// baseline (254.756 us; speedup 1.0000x reference)
//
#include <hip/hip_runtime.h>
#include <cfloat>

#define NB    32
#define ND    256
#define NK    512
#define NCOND 16
#define NHW   4096
#define PXT   64
#define MARGIN 1.3e-4f   // validated R6-R13; 2-product fast err 2*delta ~ 8.6e-5 < MARGIN
#define QCAP  16

typedef __attribute__((ext_vector_type(8))) short bf16x8;
typedef __attribute__((ext_vector_type(4))) float f32x4;

// C declared int64 in the reference; detect storage width on device.
__device__ __forceinline__ int loadC(const int* __restrict__ C, int b) {
  int orodd = 0;
#pragma unroll
  for (int i = 1; i < 32; i += 2) orodd |= C[i];
  return (orodd == 0) ? C[2 * b] : C[b];
}

// round-to-nearest-even fp32 -> bf16 (bit trick, finite inputs)
__device__ __forceinline__ unsigned short rne_bf16(float x) {
  unsigned u = __float_as_uint(x);
  u += 0x7fffu + ((u >> 16) & 1u);
  return (unsigned short)(u >> 16);
}

// Exact np-replica score, z gathered from original [b][d][n] layout.
// FP op order verbatim from the passing R5-R13 kernels.
__device__ float np_score_g(const float* __restrict__ z, size_t zoff,
                            const float* __restrict__ er, float S) {
  float P0 = 0.f, P1 = 0.f, P2 = 0.f, P3 = 0.f;
  for (int ch = 0; ch < 16; ++ch) {
    const float* eb = er + ch * 16;
    float4 e0 = *(const float4*)(eb + 0);
    float4 e1 = *(const float4*)(eb + 4);
    float4 e2 = *(const float4*)(eb + 8);
    float4 e3 = *(const float4*)(eb + 12);
    float zb[16];
#pragma unroll
    for (int q = 0; q < 16; ++q)
      zb[q] = z[zoff + (size_t)(ch * 16 + q) * NHW];
    P0 = __fadd_rn(P0, __fmul_rn(zb[12], e3.x));
    P0 = __fadd_rn(P0, __fmul_rn(zb[8],  e2.x));
    P0 = __fadd_rn(P0, __fmul_rn(zb[4],  e1.x));
    P0 = __fadd_rn(P0, __fmul_rn(zb[0],  e0.x));
    P1 = __fadd_rn(P1, __fmul_rn(zb[13], e3.y));
    P1 = __fadd_rn(P1, __fmul_rn(zb[9],  e2.y));
    P1 = __fadd_rn(P1, __fmul_rn(zb[5],  e1.y));
    P1 = __fadd_rn(P1, __fmul_rn(zb[1],  e0.y));
    P2 = __fadd_rn(P2, __fmul_rn(zb[14], e3.z));
    P2 = __fadd_rn(P2, __fmul_rn(zb[10], e2.z));
    P2 = __fadd_rn(P2, __fmul_rn(zb[6],  e1.z));
    P2 = __fadd_rn(P2, __fmul_rn(zb[2],  e0.z));
    P3 = __fadd_rn(P3, __fmul_rn(zb[15], e3.w));
    P3 = __fadd_rn(P3, __fmul_rn(zb[11], e2.w));
    P3 = __fadd_rn(P3, __fmul_rn(zb[7],  e1.w));
    P3 = __fadd_rn(P3, __fmul_rn(zb[3],  e0.w));
  }
  float G = __fadd_rn(__fadd_rn(P0, P1), __fadd_rn(P2, P3));
  return __fadd_rn(S, __fmul_rn(-2.0f, G));
}

// pre-kernel: codebook bf16-hi (RNE), k-major: whi[cond][ks=d/32][code][d%32]
__global__ __launch_bounds__(256) void k_split(
    const float* __restrict__ w, unsigned short* __restrict__ whi) {
  int i = (blockIdx.x * 256 + threadIdx.x) * 4;
  float4 v = *(const float4*)&w[i];
  int ci = i >> 17, rem = i & 131071;
  int code = rem >> 8, d = rem & 255;
  int dst = (ci << 17) + ((d >> 5) << 14) + (code << 5) + (d & 31);
  ushort4 h;
  h.x = rne_bf16(v.x); h.y = rne_bf16(v.y);
  h.z = rne_bf16(v.z); h.w = rne_bf16(v.w);
  *(ushort4*)&whi[dst] = h;
}

// swizzled ushort index into Zh/Zl: row px (256 ushorts), 8-elem chunk XOR
__device__ __forceinline__ int zofs(int px, int chunk) {
  return px * 256 + ((chunk ^ (px & 7)) * 8);
}

template <int PRE>
__global__ __launch_bounds__(512, 4) void k_score(
    const float* __restrict__ z, const int* __restrict__ Cc,
    const float* __restrict__ w, const unsigned short* __restrict__ whi,
    int* __restrict__ idxOut) {
  __shared__ __align__(16) unsigned short Zh[PXT * ND];  // 32 KB z-hi (trunc)
  __shared__ __align__(16) unsigned short Zl[PXT * ND];  // 32 KB z-lo (rne resid)
  __shared__ float Ssh[PXT];
  __shared__ float Wmin[8][32];
  __shared__ float Thr[PXT];
  __shared__ int   qcnt[PXT], KB[PXT];
  __shared__ int   qk[PXT][QCAP];                        // aliased as Rsh pre-loop

  float* Rsh = (float*)qk;     // [2][8][64] partial S sums (4 KB), dead before enqueue

  // XCD-aware bijective swizzle (nwg = 2048 = 8*256)
  int orig = blockIdx.x;
  int blk  = (orig & 7) * 256 + (orig >> 3);
  int b    = blk >> 6;
  int n0   = (blk & 63) * PXT;
  int c    = loadC(Cc, b);
  int t    = threadIdx.x;
  int lane = t & 63;
  int wv   = t >> 6;            // 0..7
  int mw   = wv >> 2;           // px half (32 px)
  int nw   = wv & 3;            // code quarter (128 codes)

  const size_t zab = (size_t)b * ND * NHW;
  const size_t cbu = (size_t)c * (NK * ND);    // whi ushort base
  const int ar0  = mw * 32 + (lane & 15);      // A px rows: ar0, ar0+16
  const int koff = (lane >> 4) * 8;

  // ---- prologue A: pre-split z tile into bf16 hi/lo LDS (one-time) ----
  {
    int px = t & 63, dg = t >> 6;
    const float* zp = z + zab + n0 + px;
#pragma unroll
    for (int cc4 = 0; cc4 < 4; ++cc4) {
      int chunk = dg * 4 + cc4;
      bf16x8 h, l;
#pragma unroll
      for (int j = 0; j < 8; ++j) {
        float v = zp[(size_t)(chunk * 8 + j) * NHW];
        unsigned u = __float_as_uint(v) & 0xffff0000u;
        h[j] = (short)(u >> 16);
        l[j] = (short)rne_bf16(v - __uint_as_float(u));
      }
      *(bf16x8*)&Zh[zofs(px, chunk)] = h;
      *(bf16x8*)&Zl[zofs(px, chunk)] = l;
    }
  }

  // ---- prologue B: S partials, thread=(px=lane, j=wv); np accumulator chains ----
  // np pwsq128: r[j] = a[j]^2; r[j] += a[8i+j]^2 (i=1..15). Fully coalesced loads.
  {
    int px = lane, j = wv;
    const float* zp = z + zab + n0 + px;
    float a0 = zp[(size_t)j * NHW];
    float r0 = __fmul_rn(a0, a0);
    float a1 = zp[(size_t)(128 + j) * NHW];
    float r1 = __fmul_rn(a1, a1);
#pragma unroll
    for (int i = 1; i < 16; ++i) {
      float v0 = zp[(size_t)(8 * i + j) * NHW];
      r0 = __fadd_rn(r0, __fmul_rn(v0, v0));
      float v1 = zp[(size_t)(128 + 8 * i + j) * NHW];
      r1 = __fadd_rn(r1, __fmul_rn(v1, v1));
    }
    Rsh[j * 64 + px]       = r0;
    Rsh[512 + j * 64 + px] = r1;
  }
  if (t < PXT) qcnt[t] = 0;
  __syncthreads();

  // combine: np tree ((r0+r1)+(r2+r3))+((r4+r5)+(r6+r7)) per 128-block, then add
  if (t < PXT) {
    int px = t;
    float pw0 = __fadd_rn(
        __fadd_rn(__fadd_rn(Rsh[0 * 64 + px], Rsh[1 * 64 + px]),
                  __fadd_rn(Rsh[2 * 64 + px], Rsh[3 * 64 + px])),
        __fadd_rn(__fadd_rn(Rsh[4 * 64 + px], Rsh[5 * 64 + px]),
                  __fadd_rn(Rsh[6 * 64 + px], Rsh[7 * 64 + px])));
    float pw1 = __fadd_rn(
        __fadd_rn(__fadd_rn(Rsh[512 + 0 * 64 + px], Rsh[512 + 1 * 64 + px]),
                  __fadd_rn(Rsh[512 + 2 * 64 + px], Rsh[512 + 3 * 64 + px])),
        __fadd_rn(__fadd_rn(Rsh[512 + 4 * 64 + px], Rsh[512 + 5 * 64 + px]),
                  __fadd_rn(Rsh[512 + 6 * 64 + px], Rsh[512 + 7 * 64 + px])));
    Ssh[px] = __fadd_rn(pw0, pw1);
  }
  __syncthreads();   // Ssh ready; Rsh (qk alias) free for enqueue later

  f32x4 acc0[8], acc1[8];
#pragma unroll
  for (int nt = 0; nt < 8; ++nt) {
    acc0[nt] = (f32x4){0.f, 0.f, 0.f, 0.f};
    acc1[nt] = (f32x4){0.f, 0.f, 0.f, 0.f};
  }

  // ---- barrier-free K-loop: A from LDS, B from global (L1/L2-hot) ----
#pragma unroll 1
  for (int ks = 0; ks < 8; ++ks) {
    int chunkA = ks * 4 + (lane >> 4);
    bf16x8 ah0 = *(const bf16x8*)&Zh[zofs(ar0,      chunkA)];
    bf16x8 al0 = *(const bf16x8*)&Zl[zofs(ar0,      chunkA)];
    bf16x8 ah1 = *(const bf16x8*)&Zh[zofs(ar0 + 16, chunkA)];
    bf16x8 al1 = *(const bf16x8*)&Zl[zofs(ar0 + 16, chunkA)];
#pragma unroll
    for (int nt = 0; nt < 8; ++nt) {
      int code = nw * 128 + nt * 16 + (lane & 15);
      bf16x8 bh;
      if constexpr (PRE) {
        bh = *(const bf16x8*)(whi + cbu + ks * (NK * 32) + code * 32 + koff);
      } else {
        const float* sf = w + ((size_t)c * NK + code) * ND + ks * 32 + koff;
        float4 f0 = *(const float4*)sf;
        float4 f1 = *(const float4*)(sf + 4);
        float xs[8] = {f0.x, f0.y, f0.z, f0.w, f1.x, f1.y, f1.z, f1.w};
#pragma unroll
        for (int q = 0; q < 8; ++q) bh[q] = (short)rne_bf16(xs[q]);
      }
      acc0[nt] = __builtin_amdgcn_mfma_f32_16x16x32_bf16(ah0, bh, acc0[nt], 0, 0, 0);
      acc0[nt] = __builtin_amdgcn_mfma_f32_16x16x32_bf16(al0, bh, acc0[nt], 0, 0, 0);
      acc1[nt] = __builtin_amdgcn_mfma_f32_16x16x32_bf16(ah1, bh, acc1[nt], 0, 0, 0);
      acc1[nt] = __builtin_amdgcn_mfma_f32_16x16x32_bf16(al1, bh, acc1[nt], 0, 0, 0);
    }
  }

  // ---- X = fl(S + fl(-2G)); per-px min over this wave's 128 codes ----
  float pmin0[4], pmin1[4], S40[4], S41[4];
#pragma unroll
  for (int r = 0; r < 4; ++r) {
    int pr = mw * 32 + (lane >> 4) * 4 + r;
    S40[r] = Ssh[pr];
    S41[r] = Ssh[pr + 16];
    pmin0[r] = FLT_MAX; pmin1[r] = FLT_MAX;
  }
#pragma unroll
  for (int nt = 0; nt < 8; ++nt)
#pragma unroll
    for (int r = 0; r < 4; ++r) {
      float X0 = __fadd_rn(S40[r], __fmul_rn(-2.0f, acc0[nt][r]));
      float X1 = __fadd_rn(S41[r], __fmul_rn(-2.0f, acc1[nt][r]));
      acc0[nt][r] = X0; acc1[nt][r] = X1;
      pmin0[r] = fminf(pmin0[r], X0);
      pmin1[r] = fminf(pmin1[r], X1);
    }
#pragma unroll
  for (int r = 0; r < 4; ++r)
#pragma unroll
    for (int off = 1; off < 16; off <<= 1) {
      pmin0[r] = fminf(pmin0[r], __shfl_xor(pmin0[r], off));
      pmin1[r] = fminf(pmin1[r], __shfl_xor(pmin1[r], off));
    }
  if ((lane & 15) == 0) {
#pragma unroll
    for (int r = 0; r < 4; ++r) {
      Wmin[wv][(lane >> 4) * 4 + r]      = pmin0[r];
      Wmin[wv][16 + (lane >> 4) * 4 + r] = pmin1[r];
    }
  }
  __syncthreads();
  if (t < PXT) {
    int m2 = (t >> 5) * 4, i = t & 31;
    Thr[t] = fminf(fminf(Wmin[m2][i], Wmin[m2 + 1][i]),
                   fminf(Wmin[m2 + 2][i], Wmin[m2 + 3][i])) + MARGIN;
  }
  __syncthreads();

  // ---- enqueue candidates ----
#pragma unroll
  for (int r = 0; r < 4; ++r) {
    int px0 = mw * 32 + (lane >> 4) * 4 + r;
    float th0 = Thr[px0], th1 = Thr[px0 + 16];
#pragma unroll
    for (int nt = 0; nt < 8; ++nt) {
      int kcode = nw * 128 + nt * 16 + (lane & 15);
      if (acc0[nt][r] <= th0) {
        int slot = atomicAdd(&qcnt[px0], 1);
        if (slot < QCAP) qk[px0][slot] = kcode;
      }
      if (acc1[nt][r] <= th1) {
        int slot = atomicAdd(&qcnt[px0 + 16], 1);
        if (slot < QCAP) qk[px0 + 16][slot] = kcode;
      }
    }
  }
  __syncthreads();

  // ---- exact np re-score (wave wv: px octet, slot = lane&7) ----
  // cnt==1 shortcut: margin proof puts np-argmin in the candidate set, so a
  // singleton needs no re-score.
  {
    int px  = wv * 8 + (lane >> 3);
    int cnt = qcnt[px]; cnt = cnt < QCAP ? cnt : QCAP;
    float S = Ssh[px];
    size_t zoff = zab + n0 + px;
    float bv = FLT_MAX; int bk = 0x7fffffff;
    int slot0 = lane & 7;
    if (cnt == 1) {
      if (slot0 == 0) { bv = 0.f; bk = qk[px][0]; }
    } else {
#pragma unroll
      for (int m = 0; m < 2; ++m) {
        int slot = slot0 + 8 * m;
        bool act = (cnt > 1) && (slot < cnt);
        if (__any(act)) {
          if (act) {
            int k = qk[px][slot];
            float v = np_score_g(z, zoff, w + ((size_t)c * NK + k) * ND, S);
            if (v < bv || (v == bv && k < bk)) { bv = v; bk = k; }
          }
        }
      }
    }
#pragma unroll
    for (int off = 1; off < 8; off <<= 1) {
      float ov = __shfl_xor(bv, off);
      int   ok = __shfl_xor(bk, off);
      if (ov < bv || (ov == bv && ok < bk)) { bv = ov; bk = ok; }
    }
    if (slot0 == 0) KB[px] = bk;
  }
  __syncthreads();

  if (t < PXT) idxOut[b * NHW + n0 + t] = KB[t];
}

// Pure-streaming gather: 2048 blocks x 256 thr, no LDS, high occupancy.
__global__ __launch_bounds__(256) void k_gather(
    const float* __restrict__ z, const int* __restrict__ Cc,
    const float* __restrict__ w, const int* __restrict__ idx,
    float* __restrict__ out) {
  int orig = blockIdx.x;
  int blk  = (orig & 7) * 256 + (orig >> 3);   // same XCD swizzle
  int b    = blk >> 6;
  int n0   = (blk & 63) * PXT;
  int c    = loadC(Cc, b);
  int t    = threadIdx.x;
  int px   = t & 63, q = t >> 6;               // q: d-quarter
  int kidx = idx[b * NHW + n0 + px];
  const float* er = w + ((size_t)c * NK + kidx) * ND + q * 64;
  const size_t OUT2 = (size_t)NB * ND * NHW;
  size_t base = (size_t)b * ND * NHW + n0 + px;
#pragma unroll
  for (int j4 = 0; j4 < 16; ++j4) {
    float4 e4 = *(const float4*)(er + j4 * 4);
    float ev[4] = {e4.x, e4.y, e4.z, e4.w};
#pragma unroll
    for (int jj = 0; jj < 4; ++jj) {
      int d = q * 64 + j4 * 4 + jj;
      float qv = ev[jj];
      float zv = z[base + (size_t)d * NHW];
      out[base + (size_t)d * NHW]        = __fadd_rn(zv, __fsub_rn(qv, zv));
      out[base + (size_t)d * NHW + OUT2] = qv;
    }
  }
}

extern "C" void kernel_launch(void* const* d_in, const int* in_sizes, int n_in,
                              void* d_out, int out_size, void* d_ws, size_t ws_size,
                              hipStream_t stream) {
  const float* z = (const float*)d_in[0];
  const int*   C = (const int*)d_in[1];
  const float* w = (const float*)d_in[2];
  float* out = (float*)d_out;

  const size_t NWEL = (size_t)NCOND * NK * ND;   // 2,097,152
  const size_t WHI_BYTES = NWEL * sizeof(unsigned short);  // 4 MB
  const size_t IDX_BYTES = (size_t)NB * NHW * sizeof(int); // 512 KB
  bool pre = ws_size >= WHI_BYTES + IDX_BYTES;

  if (pre) {
    unsigned short* whi = (unsigned short*)d_ws;
    int* idx = (int*)((char*)d_ws + WHI_BYTES);
    k_split<<<(int)(NWEL / 1024), 256, 0, stream>>>(w, whi);
    k_score<1><<<NB * (NHW / PXT), 512, 0, stream>>>(z, C, w, whi, idx);
    k_gather<<<NB * (NHW / PXT), 256, 0, stream>>>(z, C, w, idx, out);
  } else {
    int* idx = (int*)d_ws;
    k_score<0><<<NB * (NHW / PXT), 512, 0, stream>>>(z, C, w, nullptr, idx);
    k_gather<<<NB * (NHW / PXT), 256, 0, stream>>>(z, C, w, idx, out);
  }
}

// Round 15
// 218.453 us; speedup vs baseline: 1.1662x; 1.1662x over previous
//
#include <hip/hip_runtime.h>
#include <cfloat>

#define NB    32
#define ND    256
#define NK    512
#define NCOND 16
#define NHW   4096
#define PXT   32
#define MARGIN 1.3e-4f   // validated R6-R14; 2-product fast err 2*delta ~ 8.6e-5 < MARGIN
#define QCAP  16

typedef __attribute__((ext_vector_type(8))) short bf16x8;
typedef __attribute__((ext_vector_type(4))) float f32x4;

// C declared int64 in the reference; detect storage width on device.
__device__ __forceinline__ int loadC(const int* __restrict__ C, int b) {
  int orodd = 0;
#pragma unroll
  for (int i = 1; i < 32; i += 2) orodd |= C[i];
  return (orodd == 0) ? C[2 * b] : C[b];
}

// round-to-nearest-even fp32 -> bf16 (bit trick, finite inputs)
__device__ __forceinline__ unsigned short rne_bf16(float x) {
  unsigned u = __float_as_uint(x);
  u += 0x7fffu + ((u >> 16) & 1u);
  return (unsigned short)(u >> 16);
}

// Exact np-replica score, z gathered from original [b][d][n] layout.
// FP op order verbatim from the passing R5-R14 kernels.
__device__ float np_score_g(const float* __restrict__ z, size_t zoff,
                            const float* __restrict__ er, float S) {
  float P0 = 0.f, P1 = 0.f, P2 = 0.f, P3 = 0.f;
  for (int ch = 0; ch < 16; ++ch) {
    const float* eb = er + ch * 16;
    float4 e0 = *(const float4*)(eb + 0);
    float4 e1 = *(const float4*)(eb + 4);
    float4 e2 = *(const float4*)(eb + 8);
    float4 e3 = *(const float4*)(eb + 12);
    float zb[16];
#pragma unroll
    for (int q = 0; q < 16; ++q)
      zb[q] = z[zoff + (size_t)(ch * 16 + q) * NHW];
    P0 = __fadd_rn(P0, __fmul_rn(zb[12], e3.x));
    P0 = __fadd_rn(P0, __fmul_rn(zb[8],  e2.x));
    P0 = __fadd_rn(P0, __fmul_rn(zb[4],  e1.x));
    P0 = __fadd_rn(P0, __fmul_rn(zb[0],  e0.x));
    P1 = __fadd_rn(P1, __fmul_rn(zb[13], e3.y));
    P1 = __fadd_rn(P1, __fmul_rn(zb[9],  e2.y));
    P1 = __fadd_rn(P1, __fmul_rn(zb[5],  e1.y));
    P1 = __fadd_rn(P1, __fmul_rn(zb[1],  e0.y));
    P2 = __fadd_rn(P2, __fmul_rn(zb[14], e3.z));
    P2 = __fadd_rn(P2, __fmul_rn(zb[10], e2.z));
    P2 = __fadd_rn(P2, __fmul_rn(zb[6],  e1.z));
    P2 = __fadd_rn(P2, __fmul_rn(zb[2],  e0.z));
    P3 = __fadd_rn(P3, __fmul_rn(zb[15], e3.w));
    P3 = __fadd_rn(P3, __fmul_rn(zb[11], e2.w));
    P3 = __fadd_rn(P3, __fmul_rn(zb[7],  e1.w));
    P3 = __fadd_rn(P3, __fmul_rn(zb[3],  e0.w));
  }
  float G = __fadd_rn(__fadd_rn(P0, P1), __fadd_rn(P2, P3));
  return __fadd_rn(S, __fmul_rn(-2.0f, G));
}

// pre-kernel: codebook bf16-hi (RNE), k-major: whi[cond][ks=d/32][code][d%32]
__global__ __launch_bounds__(256) void k_split(
    const float* __restrict__ w, unsigned short* __restrict__ whi) {
  int i = (blockIdx.x * 256 + threadIdx.x) * 4;
  float4 v = *(const float4*)&w[i];
  int ci = i >> 17, rem = i & 131071;
  int code = rem >> 8, d = rem & 255;
  int dst = (ci << 17) + ((d >> 5) << 14) + (code << 5) + (d & 31);
  ushort4 h;
  h.x = rne_bf16(v.x); h.y = rne_bf16(v.y);
  h.z = rne_bf16(v.z); h.w = rne_bf16(v.w);
  *(ushort4*)&whi[dst] = h;
}

// swizzled ushort index into Zh/Zl: row px (256 ushorts), 8-elem chunk XOR
__device__ __forceinline__ int zofs(int px, int chunk) {
  return px * 256 + ((chunk ^ (px & 7)) * 8);
}

template <int PRE>
__global__ __launch_bounds__(256, 4) void k_vq(
    const float* __restrict__ z, const int* __restrict__ Cc,
    const float* __restrict__ w, const unsigned short* __restrict__ whi,
    float* __restrict__ out) {
  __shared__ __align__(16) unsigned short Zh[PXT * ND];  // 16 KB z-hi (trunc)
  __shared__ __align__(16) unsigned short Zl[PXT * ND];  // 16 KB z-lo (rne resid)
  __shared__ float Ssh[PXT];
  __shared__ float Wmin[4][PXT];
  __shared__ float Thr[PXT];
  __shared__ int   qcnt[PXT], KB[PXT];
  __shared__ int   qk[PXT][QCAP];                        // aliased as Rsh pre-loop

  float* Rsh = (float*)qk;     // [2][8][32] partial S sums (2 KB), dead pre-enqueue

  // XCD-aware bijective swizzle (nwg = 4096 = 8*512)
  int orig = blockIdx.x;
  int blk  = (orig & 7) * 512 + (orig >> 3);
  int b    = blk >> 7;
  int n0   = (blk & 127) * PXT;
  int c    = loadC(Cc, b);
  int t    = threadIdx.x;       // 0..255
  int lane = t & 63;
  int wv   = t >> 6;            // 0..3: code quarter (128 codes), all 32 px

  const size_t zab = (size_t)b * ND * NHW;
  const size_t cbu = (size_t)c * (NK * ND);    // whi ushort base
  const int ar0  = lane & 15;                  // A px rows: ar0, ar0+16
  const int koff = (lane >> 4) * 8;

  // ---- prologue A: pre-split z tile into bf16 hi/lo LDS (one-time) ----
  {
    int px = t & 31, dg = t >> 5;              // 8 d-groups
    const float* zp = z + zab + n0 + px;
#pragma unroll
    for (int cc4 = 0; cc4 < 4; ++cc4) {
      int chunk = dg * 4 + cc4;
      bf16x8 h, l;
#pragma unroll
      for (int j = 0; j < 8; ++j) {
        float v = zp[(size_t)(chunk * 8 + j) * NHW];
        unsigned u = __float_as_uint(v) & 0xffff0000u;
        h[j] = (short)(u >> 16);
        l[j] = (short)rne_bf16(v - __uint_as_float(u));
      }
      *(bf16x8*)&Zh[zofs(px, chunk)] = h;
      *(bf16x8*)&Zl[zofs(px, chunk)] = l;
    }
  }

  // ---- prologue B: S partials, thread=(px=t&31, j=t>>5); np chains, coalesced ----
  {
    int px = t & 31, j = t >> 5;
    const float* zp = z + zab + n0 + px;
    float a0 = zp[(size_t)j * NHW];
    float r0 = __fmul_rn(a0, a0);
    float a1 = zp[(size_t)(128 + j) * NHW];
    float r1 = __fmul_rn(a1, a1);
#pragma unroll
    for (int i = 1; i < 16; ++i) {
      float v0 = zp[(size_t)(8 * i + j) * NHW];
      r0 = __fadd_rn(r0, __fmul_rn(v0, v0));
      float v1 = zp[(size_t)(128 + 8 * i + j) * NHW];
      r1 = __fadd_rn(r1, __fmul_rn(v1, v1));
    }
    Rsh[j * 32 + px]       = r0;
    Rsh[256 + j * 32 + px] = r1;
  }
  if (t < PXT) qcnt[t] = 0;
  __syncthreads();

  // combine: np tree ((r0+r1)+(r2+r3))+((r4+r5)+(r6+r7)) per 128-block, then add
  if (t < PXT) {
    int px = t;
    float pw0 = __fadd_rn(
        __fadd_rn(__fadd_rn(Rsh[0 * 32 + px], Rsh[1 * 32 + px]),
                  __fadd_rn(Rsh[2 * 32 + px], Rsh[3 * 32 + px])),
        __fadd_rn(__fadd_rn(Rsh[4 * 32 + px], Rsh[5 * 32 + px]),
                  __fadd_rn(Rsh[6 * 32 + px], Rsh[7 * 32 + px])));
    float pw1 = __fadd_rn(
        __fadd_rn(__fadd_rn(Rsh[256 + 0 * 32 + px], Rsh[256 + 1 * 32 + px]),
                  __fadd_rn(Rsh[256 + 2 * 32 + px], Rsh[256 + 3 * 32 + px])),
        __fadd_rn(__fadd_rn(Rsh[256 + 4 * 32 + px], Rsh[256 + 5 * 32 + px]),
                  __fadd_rn(Rsh[256 + 6 * 32 + px], Rsh[256 + 7 * 32 + px])));
    Ssh[px] = __fadd_rn(pw0, pw1);
  }
  __syncthreads();   // Ssh ready; Rsh (qk alias) free for enqueue later

  f32x4 acc0[8], acc1[8];
#pragma unroll
  for (int nt = 0; nt < 8; ++nt) {
    acc0[nt] = (f32x4){0.f, 0.f, 0.f, 0.f};
    acc1[nt] = (f32x4){0.f, 0.f, 0.f, 0.f};
  }

  // ---- barrier-free K-loop: A from LDS, B from global (L1/L2-hot) ----
#pragma unroll 1
  for (int ks = 0; ks < 8; ++ks) {
    int chunkA = ks * 4 + (lane >> 4);
    bf16x8 ah0 = *(const bf16x8*)&Zh[zofs(ar0,      chunkA)];
    bf16x8 al0 = *(const bf16x8*)&Zl[zofs(ar0,      chunkA)];
    bf16x8 ah1 = *(const bf16x8*)&Zh[zofs(ar0 + 16, chunkA)];
    bf16x8 al1 = *(const bf16x8*)&Zl[zofs(ar0 + 16, chunkA)];
#pragma unroll
    for (int nt = 0; nt < 8; ++nt) {
      int code = wv * 128 + nt * 16 + (lane & 15);
      bf16x8 bh;
      if constexpr (PRE) {
        bh = *(const bf16x8*)(whi + cbu + ks * (NK * 32) + code * 32 + koff);
      } else {
        const float* sf = w + ((size_t)c * NK + code) * ND + ks * 32 + koff;
        float4 f0 = *(const float4*)sf;
        float4 f1 = *(const float4*)(sf + 4);
        float xs[8] = {f0.x, f0.y, f0.z, f0.w, f1.x, f1.y, f1.z, f1.w};
#pragma unroll
        for (int q = 0; q < 8; ++q) bh[q] = (short)rne_bf16(xs[q]);
      }
      acc0[nt] = __builtin_amdgcn_mfma_f32_16x16x32_bf16(ah0, bh, acc0[nt], 0, 0, 0);
      acc0[nt] = __builtin_amdgcn_mfma_f32_16x16x32_bf16(al0, bh, acc0[nt], 0, 0, 0);
      acc1[nt] = __builtin_amdgcn_mfma_f32_16x16x32_bf16(ah1, bh, acc1[nt], 0, 0, 0);
      acc1[nt] = __builtin_amdgcn_mfma_f32_16x16x32_bf16(al1, bh, acc1[nt], 0, 0, 0);
    }
  }

  // ---- X = fl(S + fl(-2G)); per-px min over this wave's 128 codes ----
  float pmin0[4], pmin1[4], S40[4], S41[4];
#pragma unroll
  for (int r = 0; r < 4; ++r) {
    int pr = (lane >> 4) * 4 + r;
    S40[r] = Ssh[pr];
    S41[r] = Ssh[pr + 16];
    pmin0[r] = FLT_MAX; pmin1[r] = FLT_MAX;
  }
#pragma unroll
  for (int nt = 0; nt < 8; ++nt)
#pragma unroll
    for (int r = 0; r < 4; ++r) {
      float X0 = __fadd_rn(S40[r], __fmul_rn(-2.0f, acc0[nt][r]));
      float X1 = __fadd_rn(S41[r], __fmul_rn(-2.0f, acc1[nt][r]));
      acc0[nt][r] = X0; acc1[nt][r] = X1;
      pmin0[r] = fminf(pmin0[r], X0);
      pmin1[r] = fminf(pmin1[r], X1);
    }
#pragma unroll
  for (int r = 0; r < 4; ++r)
#pragma unroll
    for (int off = 1; off < 16; off <<= 1) {
      pmin0[r] = fminf(pmin0[r], __shfl_xor(pmin0[r], off));
      pmin1[r] = fminf(pmin1[r], __shfl_xor(pmin1[r], off));
    }
  if ((lane & 15) == 0) {
#pragma unroll
    for (int r = 0; r < 4; ++r) {
      Wmin[wv][(lane >> 4) * 4 + r]      = pmin0[r];
      Wmin[wv][16 + (lane >> 4) * 4 + r] = pmin1[r];
    }
  }
  __syncthreads();
  if (t < PXT) {
    Thr[t] = fminf(fminf(Wmin[0][t], Wmin[1][t]),
                   fminf(Wmin[2][t], Wmin[3][t])) + MARGIN;
  }
  __syncthreads();

  // ---- enqueue candidates ----
#pragma unroll
  for (int r = 0; r < 4; ++r) {
    int px0 = (lane >> 4) * 4 + r;
    float th0 = Thr[px0], th1 = Thr[px0 + 16];
#pragma unroll
    for (int nt = 0; nt < 8; ++nt) {
      int kcode = wv * 128 + nt * 16 + (lane & 15);
      if (acc0[nt][r] <= th0) {
        int slot = atomicAdd(&qcnt[px0], 1);
        if (slot < QCAP) qk[px0][slot] = kcode;
      }
      if (acc1[nt][r] <= th1) {
        int slot = atomicAdd(&qcnt[px0 + 16], 1);
        if (slot < QCAP) qk[px0 + 16][slot] = kcode;
      }
    }
  }
  __syncthreads();

  // ---- exact np re-score (wave wv: px octet, slot = lane&7); cnt==1 shortcut ----
  {
    int px  = wv * 8 + (lane >> 3);
    int cnt = qcnt[px]; cnt = cnt < QCAP ? cnt : QCAP;
    float S = Ssh[px];
    size_t zoff = zab + n0 + px;
    float bv = FLT_MAX; int bk = 0x7fffffff;
    int slot0 = lane & 7;
    if (cnt == 1) {
      if (slot0 == 0) { bv = 0.f; bk = qk[px][0]; }
    } else {
#pragma unroll
      for (int m = 0; m < 2; ++m) {
        int slot = slot0 + 8 * m;
        bool act = slot < cnt;
        if (__any(act)) {
          if (act) {
            int k = qk[px][slot];
            float v = np_score_g(z, zoff, w + ((size_t)c * NK + k) * ND, S);
            if (v < bv || (v == bv && k < bk)) { bv = v; bk = k; }
          }
        }
      }
    }
#pragma unroll
    for (int off = 1; off < 8; off <<= 1) {
      float ov = __shfl_xor(bv, off);
      int   ok = __shfl_xor(bk, off);
      if (ov < bv || (ov == bv && ok < bk)) { bv = ov; bk = ok; }
    }
    if (slot0 == 0) KB[px] = bk;
  }
  __syncthreads();

  // ---- gather + transpose-write both outputs (z re-read, L2-hot) ----
  {
    int px = t & 31, dg = t >> 5;
    int kidx = KB[px];
    const float* er = w + ((size_t)c * NK + kidx) * ND;
    const size_t OUT2 = (size_t)NB * ND * NHW;
    size_t base = zab + n0 + px;
#pragma unroll
    for (int j = 0; j < 32; ++j) {
      int d = dg * 32 + j;
      float q  = er[d];
      float zv = z[base + (size_t)d * NHW];
      out[base + (size_t)d * NHW]        = __fadd_rn(zv, __fsub_rn(q, zv));
      out[base + (size_t)d * NHW + OUT2] = q;
    }
  }
}

extern "C" void kernel_launch(void* const* d_in, const int* in_sizes, int n_in,
                              void* d_out, int out_size, void* d_ws, size_t ws_size,
                              hipStream_t stream) {
  const float* z = (const float*)d_in[0];
  const int*   C = (const int*)d_in[1];
  const float* w = (const float*)d_in[2];
  float* out = (float*)d_out;

  const size_t NWEL = (size_t)NCOND * NK * ND;   // 2,097,152
  unsigned short* whi = (unsigned short*)d_ws;
  bool pre = ws_size >= NWEL * sizeof(unsigned short);  // 4 MB

  if (pre) {
    k_split<<<(int)(NWEL / 1024), 256, 0, stream>>>(w, whi);
    k_vq<1><<<NB * (NHW / PXT), 256, 0, stream>>>(z, C, w, whi, out);
  } else {
    k_vq<0><<<NB * (NHW / PXT), 256, 0, stream>>>(z, C, w, nullptr, out);
  }
}